// Round 13
// baseline (387.674 us; speedup 1.0000x reference)
//
#include <hip/hip_runtime.h>
#include <hip/hip_bf16.h>
#include <hip/hip_cooperative_groups.h>
#include <math.h>

namespace cg = cooperative_groups;

#define NB 4
#define CC 128
#define HH 64
#define WW 64
#define HEADS 4
#define KS 7
#define DD 32
#define HW 4096
#define MTOT 16384   // NB*HW

typedef unsigned short BF;
typedef short short8 __attribute__((ext_vector_type(8)));
typedef float floatx4 __attribute__((ext_vector_type(4)));

__device__ __forceinline__ float gelu_f(float x) {
    return 0.5f * x * (1.0f + erff(x * 0.70710678118654752440f));
}

__device__ __forceinline__ BF f2bf(float f) {
    union { float f; unsigned u; } a; a.f = f;
    unsigned u = a.u;
    unsigned r = u + 0x7FFFu + ((u >> 16) & 1u);   // RNE
    return (BF)(r >> 16);
}

__device__ __forceinline__ float bf2f(BF v) {
    return __uint_as_float(((unsigned)v) << 16);
}

#define LDK 40
#define LDK128 136

struct Params {
    const float* x;
    const float* ln1_w; const float* ln1_b;
    const float* ln2_w; const float* ln2_b;
    const float* qkv_b; const float* proj_b;
    const float* rpb;
    const float* conv1_b; const float* conv2_b;
    const float* ca1_w; const float* ca1_b;
    const float* ca2_w; const float* ca2_b;
    const float* fc1_b; const float* fc2_b;
    const float* qkv_w; const float* conv1_w; const float* conv2_w;
    const float* proj_w; const float* fc1_w; const float* fc2_w;
    BF* xn; BF* qkv; BF* tbuf; BF* na;
    float* part;
    BF* qkvT; BF* c1T; BF* c2T; BF* projT2; BF* fc1T2; BF* fc2T2;
    float* out;
};

// LDS arena: max over phases = na's 68260 B
#define SMEM_BYTES 68352

__global__ __launch_bounds__(256, 2) void mega_kernel(Params p)
{
    __shared__ __align__(16) char smem[SMEM_BYTES];
    const int blk = blockIdx.x;          // 0..511
    const int t   = threadIdx.x;
    const int w = t >> 6, lane = t & 63, quad = lane >> 4, r16 = lane & 15;
    cg::grid_group grid = cg::this_grid();

    // ================= P0: LN1 transpose-tile + weight prep ===========
    {
        float* xt  = (float*)smem;              // [128][33]
        float* mus = (float*)(smem + 16896);    // [32]
        float* rss = (float*)(smem + 17024);    // [32]
        const int n  = blk >> 7;
        const int p0 = (blk & 127) * 32;
        if (blk < 4 && t < 128) p.part[blk * CC + t] = 0.f;

        {
            int pp = t & 31, c8 = t >> 5;
            #pragma unroll 4
            for (int it = 0; it < 16; it++) {
                int c = it * 8 + c8;
                xt[c * 33 + pp] = p.x[(size_t)(n * CC + c) * HW + p0 + pp];
            }
        }
        // weight prep: 400 elems per block (204800 / 512)
        for (int idx = blk * 400 + t; idx < (blk + 1) * 400; idx += 256) {
            if (idx < 49152) {                    // qkvT [384][128]
                int l = idx, nn = l >> 7, k = l & 127;
                p.qkvT[l] = f2bf(p.qkv_w[k * 384 + nn]);
            } else if (idx < 53248) {             // c1T [32][128]
                int l = idx - 49152, nn = l >> 7, k = l & 127;
                p.c1T[l] = f2bf(p.conv1_w[k * 32 + nn]);
            } else if (idx < 57344) {             // c2T [128][32]
                int l = idx - 53248, nn = l >> 5, k = l & 31;
                p.c2T[l] = f2bf(p.conv2_w[k * 128 + nn]);
            } else if (idx < 73728) {             // projT2 [4][128][32]
                int l = idx - 57344, kk = l & 31, nn = (l >> 5) & 127, ks = l >> 12;
                p.projT2[l] = f2bf(p.proj_w[(ks * 32 + kk) * 128 + nn]);
            } else if (idx < 139264) {            // fc1T2 [4][512][32]
                int l = idx - 73728, kk = l & 31, nn = (l >> 5) & 511, ks = l >> 14;
                p.fc1T2[l] = f2bf(p.fc1_w[(ks * 32 + kk) * 512 + nn]);
            } else if (idx < 204800) {            // fc2T2 [16][128][32]
                int l = idx - 139264, kk = l & 31, nn = (l >> 5) & 127, ks = l >> 12;
                p.fc2T2[l] = f2bf(p.fc2_w[(ks * 32 + kk) * 128 + nn]);
            }
        }
        __syncthreads();
        {
            int pp2 = t >> 3, cb = t & 7;
            float s = 0.f;
            #pragma unroll
            for (int u = 0; u < 16; u++) s += xt[(cb + u * 8) * 33 + pp2];
            s += __shfl_xor(s, 1); s += __shfl_xor(s, 2); s += __shfl_xor(s, 4);
            float mu = s * (1.0f / CC);
            float v = 0.f;
            #pragma unroll
            for (int u = 0; u < 16; u++) { float d = xt[(cb + u * 8) * 33 + pp2] - mu; v += d * d; }
            v += __shfl_xor(v, 1); v += __shfl_xor(v, 2); v += __shfl_xor(v, 4);
            if (cb == 0) { mus[pp2] = mu; rss[pp2] = rsqrtf(v * (1.0f / CC) + 1e-5f); }
        }
        __syncthreads();
        {
            #pragma unroll
            for (int it = 0; it < 2; it++) {
                int pp2 = (t >> 4) + it * 16;
                int c0  = (t & 15) * 8;
                float mu = mus[pp2], rs = rss[pp2];
                int m = n * HW + p0 + pp2;
                short8 o;
                #pragma unroll
                for (int u = 0; u < 8; u++)
                    o[u] = (short)f2bf((xt[(c0 + u) * 33 + pp2] - mu) * rs * p.ln1_w[c0 + u] + p.ln1_b[c0 + u]);
                *(short8*)(p.xn + (size_t)m * CC + c0) = o;
            }
        }
    }
    grid.sync();

    // ================= P1: qkv GEMM + conv-MLP ========================
    for (int bid = blk; bid < 1792; bid += 512) {
        if (bid < 1536) {
            // ---- qkv tile ----
            BF* Bl = (BF*)smem;   // [64][LDK128]
            const int col0 = (bid % 6) * 64;
            const int row0 = (bid / 6) * 64;
            {
                int nn = t >> 2, kk = (t & 3) * 32;
                const BF* src = p.qkvT + (size_t)(col0 + nn) * 128 + kk;
                #pragma unroll
                for (int u = 0; u < 4; u++)
                    *(uint4*)(Bl + nn * LDK128 + kk + u * 8) = *(const uint4*)(src + u * 8);
            }
            __syncthreads();
            floatx4 acc[4] = {};
            const BF* arow = p.xn + (size_t)(row0 + w * 16 + r16) * CC;
            #pragma unroll
            for (int ks = 0; ks < 4; ks++) {
                short8 af = *(const short8*)(arow + ks * 32 + quad * 8);
                #pragma unroll
                for (int nt = 0; nt < 4; nt++) {
                    short8 bf = *(const short8*)(Bl + (nt * 16 + r16) * LDK128 + ks * 32 + quad * 8);
                    acc[nt] = __builtin_amdgcn_mfma_f32_16x16x32_bf16(af, bf, acc[nt], 0, 0, 0);
                }
            }
            #pragma unroll
            for (int nt = 0; nt < 4; nt++) {
                int col = col0 + nt * 16 + r16;
                float bv = p.qkv_b[col];
                #pragma unroll
                for (int reg = 0; reg < 4; reg++) {
                    int row = row0 + w * 16 + quad * 4 + reg;
                    p.qkv[(size_t)row * 384 + col] = f2bf(acc[nt][reg] + bv);
                }
            }
            __syncthreads();
        } else {
            // ---- conv tile ----
            BF*    W1l = (BF*)smem;                  // [32][LDK128]
            BF*    W2l = (BF*)(smem + 8704);         // [128][LDK]
            BF*    Hl  = (BF*)(smem + 18944);        // [64][LDK]
            float* red = (float*)(smem + 24064);     // [4][128]
            const int row0 = (bid - 1536) * 64;
            {
                #pragma unroll
                for (int it = 0; it < 2; it++) {
                    int idx = it * 256 + t;
                    int nn = idx >> 4, u = idx & 15;
                    *(uint4*)(W1l + nn * LDK128 + u * 8) = *(const uint4*)(p.c1T + nn * 128 + u * 8);
                }
            }
            {
                #pragma unroll
                for (int it = 0; it < 2; it++) {
                    int idx = it * 256 + t;
                    int nn = idx >> 2, u = idx & 3;
                    *(uint4*)(W2l + nn * LDK + u * 8) = *(const uint4*)(p.c2T + nn * 32 + u * 8);
                }
            }
            __syncthreads();
            floatx4 a1[2] = {};
            const BF* arow = p.xn + (size_t)(row0 + w * 16 + r16) * CC;
            #pragma unroll
            for (int ks = 0; ks < 4; ks++) {
                short8 af = *(const short8*)(arow + ks * 32 + quad * 8);
                #pragma unroll
                for (int nt = 0; nt < 2; nt++) {
                    short8 bf = *(const short8*)(W1l + (nt * 16 + r16) * LDK128 + ks * 32 + quad * 8);
                    a1[nt] = __builtin_amdgcn_mfma_f32_16x16x32_bf16(af, bf, a1[nt], 0, 0, 0);
                }
            }
            #pragma unroll
            for (int nt = 0; nt < 2; nt++) {
                int col = nt * 16 + r16;
                float bv = p.conv1_b[col];
                #pragma unroll
                for (int reg = 0; reg < 4; reg++)
                    Hl[(w * 16 + quad * 4 + reg) * LDK + col] = f2bf(gelu_f(a1[nt][reg] + bv));
            }
            __syncthreads();
            floatx4 a2[8] = {};
            short8 af2 = *(const short8*)(Hl + (w * 16 + r16) * LDK + quad * 8);
            #pragma unroll
            for (int nt = 0; nt < 8; nt++) {
                short8 bf = *(const short8*)(W2l + (nt * 16 + r16) * LDK + quad * 8);
                a2[nt] = __builtin_amdgcn_mfma_f32_16x16x32_bf16(af2, bf, a2[nt], 0, 0, 0);
            }
            #pragma unroll
            for (int nt = 0; nt < 8; nt++) {
                int col = nt * 16 + r16;
                float bv = p.conv2_b[col];
                float s = 0.f;
                #pragma unroll
                for (int reg = 0; reg < 4; reg++) {
                    int row = row0 + w * 16 + quad * 4 + reg;
                    float v = a2[nt][reg] + bv;
                    p.tbuf[(size_t)row * CC + col] = f2bf(v);
                    s += v;
                }
                s += __shfl_xor(s, 16);
                s += __shfl_xor(s, 32);
                if (lane < 16) red[w * 128 + col] = s;
            }
            __syncthreads();
            if (t < 128) {
                float cs = red[t] + red[128 + t] + red[256 + t] + red[384 + t];
                atomicAdd(&p.part[(row0 >> 12) * CC + t], cs);
            }
            __syncthreads();
        }
    }
    grid.sync();

    // ================= P2: MFMA neighborhood attention ================
    for (int bid = blk; bid < 1024; bid += 512) {
        BF*    Kt = (BF*)smem;               // [224][40]
        BF*    Vt = (BF*)(smem + 17920);     // [32][232]
        BF*    Qb = (BF*)(smem + 32768);     // [64][40]
        BF*    Pl = (BF*)(smem + 37888);     // [4][16][232]
        float* rb = (float*)(smem + 67584);  // [169]

        const int h = bid & 3;
        const int tile = bid >> 2;
        const int n = tile >> 6;
        const int ti = (tile >> 3) & 7, tj = tile & 7;
        const int i0 = ti * 8, j0 = tj * 8;
        const int wi0 = max(i0 - 3, 0), wj0 = max(j0 - 3, 0);
        const int R  = min(wi0 + 13, 63) - wi0 + 1;
        const int Rj = min(wj0 + 13, 63) - wj0 + 1;

        for (int idx = t; idx < 896; idx += 256) {
            int key = idx >> 2, ch = idx & 3;
            int kr = key >> 4, kc = key & 15;
            uint4 v = {0u, 0u, 0u, 0u};
            if (kr < R && kc < Rj) {
                size_t pix = (size_t)((n * HH + wi0 + kr) * WW + wj0 + kc);
                v = *(const uint4*)(p.qkv + pix * 384 + 128 + h * DD + ch * 8);
            }
            *(uint4*)(Kt + key * 40 + ch * 8) = v;
        }
        for (int idx = t; idx < 896; idx += 256) {
            int key = idx >> 2, ch = idx & 3;
            int kr = key >> 4, kc = key & 15;
            if (kr < R && kc < Rj) {
                size_t pix = (size_t)((n * HH + wi0 + kr) * WW + wj0 + kc);
                uint4 v = *(const uint4*)(p.qkv + pix * 384 + 256 + h * DD + ch * 8);
                const BF* pv = (const BF*)&v;
                #pragma unroll
                for (int u = 0; u < 8; u++) Vt[(ch * 8 + u) * 232 + key] = pv[u];
            } else {
                #pragma unroll
                for (int u = 0; u < 8; u++) Vt[(ch * 8 + u) * 232 + key] = 0;
            }
        }
        {
            int q = t >> 2, ch = t & 3;
            size_t mq = (size_t)((n * HH + i0 + (q >> 3)) * WW + j0 + (q & 7));
            *(uint4*)(Qb + q * 40 + ch * 8) = *(const uint4*)(p.qkv + mq * 384 + h * DD + ch * 8);
        }
        if (t < 169) rb[t] = p.rpb[h * 169 + t];
        __syncthreads();

        int oi[4], cok[4], bj0[4], ai_[4];
        #pragma unroll
        for (int reg = 0; reg < 4; reg++) {
            int q = w * 16 + quad * 4 + reg;
            int i = i0 + (q >> 3), j = j0 + (q & 7);
            int ni = min(max(i - 3, 0), HH - KS), nj = min(max(j - 3, 0), WW - KS);
            oi[reg]  = ni - wi0;
            ai_[reg] = ni - i + 6;
            int dc = r16 - (nj - wj0);
            cok[reg] = ((unsigned)dc < 7u) ? 1 : 0;
            bj0[reg] = min(max(dc + (nj - j + 6), 0), 12);
        }

        short8 aq = *(const short8*)(Qb + (w * 16 + r16) * 40 + quad * 8);
        floatx4 S[14];
        #pragma unroll
        for (int nt = 0; nt < 14; nt++) {
            floatx4 z = {0.f, 0.f, 0.f, 0.f};
            short8 bk = *(const short8*)(Kt + (nt * 16 + r16) * 40 + quad * 8);
            S[nt] = __builtin_amdgcn_mfma_f32_16x16x32_bf16(aq, bk, z, 0, 0, 0);
        }
        const float scale = 0.17677669529663688110f;
        #pragma unroll
        for (int nt = 0; nt < 14; nt++) {
            #pragma unroll
            for (int reg = 0; reg < 4; reg++) {
                int dr = nt - oi[reg];
                bool ok = ((unsigned)dr < 7u) && cok[reg];
                int bi = min(max(dr + ai_[reg], 0), 12);
                float bias = rb[bi * 13 + bj0[reg]];
                S[nt][reg] = ok ? fmaf(S[nt][reg], scale, bias) : -1e30f;
            }
        }
        float rinv[4];
        #pragma unroll
        for (int reg = 0; reg < 4; reg++) {
            float m = S[0][reg];
            #pragma unroll
            for (int nt = 1; nt < 14; nt++) m = fmaxf(m, S[nt][reg]);
            m = fmaxf(m, __shfl_xor(m, 1));
            m = fmaxf(m, __shfl_xor(m, 2));
            m = fmaxf(m, __shfl_xor(m, 4));
            m = fmaxf(m, __shfl_xor(m, 8));
            float s = 0.f;
            #pragma unroll
            for (int nt = 0; nt < 14; nt++) {
                float e = __expf(S[nt][reg] - m);
                S[nt][reg] = e;
                s += e;
            }
            s += __shfl_xor(s, 1);
            s += __shfl_xor(s, 2);
            s += __shfl_xor(s, 4);
            s += __shfl_xor(s, 8);
            rinv[reg] = 1.0f / s;
        }
        #pragma unroll
        for (int nt = 0; nt < 14; nt++)
            #pragma unroll
            for (int reg = 0; reg < 4; reg++)
                Pl[(w * 16 + quad * 4 + reg) * 232 + nt * 16 + r16] = f2bf(S[nt][reg] * rinv[reg]);

        floatx4 O0 = {0.f, 0.f, 0.f, 0.f}, O1 = {0.f, 0.f, 0.f, 0.f};
        #pragma unroll
        for (int ks = 0; ks < 7; ks++) {
            short8 ap = *(const short8*)(Pl + (w * 16 + r16) * 232 + ks * 32 + quad * 8);
            short8 b0 = *(const short8*)(Vt + r16 * 232 + ks * 32 + quad * 8);
            short8 b1 = *(const short8*)(Vt + (16 + r16) * 232 + ks * 32 + quad * 8);
            O0 = __builtin_amdgcn_mfma_f32_16x16x32_bf16(ap, b0, O0, 0, 0, 0);
            O1 = __builtin_amdgcn_mfma_f32_16x16x32_bf16(ap, b1, O1, 0, 0, 0);
        }
        #pragma unroll
        for (int reg = 0; reg < 4; reg++) {
            int q = w * 16 + quad * 4 + reg;
            size_t m = (size_t)((n * HH + i0 + (q >> 3)) * WW + j0 + (q & 7));
            p.na[m * CC + h * DD + r16]      = f2bf(O0[reg]);
            p.na[m * CC + h * DD + 16 + r16] = f2bf(O1[reg]);
        }
        __syncthreads();
    }
    grid.sync();

    // ================= P3: tail (proj+gate+x2+LN2+fc1+fc2+store) ======
    {
        float* xs   = (float*)smem;              // [32][132] (overlaid w/ st)
        float* st   = (float*)smem;              // [128][34]
        BF*    ln2l = (BF*)(smem + 17408);       // [32][136]
        BF*    hl   = (BF*)(smem + 26112);       // [32][520]
        float* gs   = (float*)(smem + 59392);    // [128]
        float* h1s  = (float*)(smem + 59904);    // [7]
        float* gl   = (float*)(smem + 59936);    // [128]
        float* S1   = (float*)(smem + 60448);    // [4][16]
        float* S2   = (float*)(smem + 60704);    // [4][16]

        const int row0 = blk * 32;
        const int n = row0 >> 12, p0 = row0 & 4095;
        const int mt = w & 1, nh = w >> 1;
        const int lr0 = mt * 16;

        #pragma unroll
        for (int it = 0; it < 4; it++) {
            int idx4 = it * 256 + t;
            int p4 = idx4 & 7, c = idx4 >> 3;
            float4 v = *(const float4*)(p.x + (size_t)(n * CC + c) * HW + p0 + p4 * 4);
            xs[(p4 * 4 + 0) * 132 + c] = v.x; xs[(p4 * 4 + 1) * 132 + c] = v.y;
            xs[(p4 * 4 + 2) * 132 + c] = v.z; xs[(p4 * 4 + 3) * 132 + c] = v.w;
        }
        if (t < 128) gs[t] = p.part[n * CC + t] * (1.0f / HW);
        __syncthreads();
        if (t < 7) {
            float a = p.ca1_b[t];
            for (int k = 0; k < 128; k++) a += gs[k] * p.ca1_w[k * 7 + t];
            h1s[t] = fmaxf(a, 0.f);
        }
        __syncthreads();
        if (t < 128) {
            float o = p.ca2_b[t];
            #pragma unroll
            for (int r = 0; r < 7; r++) o += h1s[r] * p.ca2_w[r * 128 + t];
            gl[t] = 1.0f / (1.0f + expf(-o));
        }

        floatx4 acc[4] = {};
        const BF* arow = p.na + (size_t)(row0 + lr0 + r16) * CC;
        #pragma unroll
        for (int ks = 0; ks < 4; ks++) {
            short8 af = *(const short8*)(arow + ks * 32 + quad * 8);
            #pragma unroll
            for (int nt = 0; nt < 4; nt++) {
                int col = nh * 64 + nt * 16 + r16;
                short8 bf = *(const short8*)(p.projT2 + ((size_t)(ks * 128 + col)) * 32 + quad * 8);
                acc[nt] = __builtin_amdgcn_mfma_f32_16x16x32_bf16(af, bf, acc[nt], 0, 0, 0);
            }
        }
        __syncthreads();   // gl ready

        float x2r[4][4];
        float s1[4] = {0.f, 0.f, 0.f, 0.f}, s2[4] = {0.f, 0.f, 0.f, 0.f};
        #pragma unroll
        for (int nt = 0; nt < 4; nt++) {
            int col = nh * 64 + nt * 16 + r16;
            float bv = p.proj_b[col], gv = gl[col];
            #pragma unroll
            for (int reg = 0; reg < 4; reg++) {
                int lr = lr0 + quad * 4 + reg;
                float tv = bf2f(p.tbuf[(size_t)(row0 + lr) * CC + col]);
                float v = acc[nt][reg] + bv + xs[lr * 132 + col] + 0.02f * tv * gv;
                x2r[nt][reg] = v;
                s1[reg] += v; s2[reg] += v * v;
            }
        }
        #pragma unroll
        for (int reg = 0; reg < 4; reg++) {
            #pragma unroll
            for (int off = 8; off; off >>= 1) {
                s1[reg] += __shfl_xor(s1[reg], off);
                s2[reg] += __shfl_xor(s2[reg], off);
            }
        }
        if (r16 == 0) {
            #pragma unroll
            for (int reg = 0; reg < 4; reg++) {
                S1[w * 16 + quad * 4 + reg] = s1[reg];
                S2[w * 16 + quad * 4 + reg] = s2[reg];
            }
        }
        __syncthreads();
        const int pw = w ^ 2;
        float mu[4], rr[4];
        #pragma unroll
        for (int reg = 0; reg < 4; reg++) {
            int r = quad * 4 + reg;
            float t1 = S1[w * 16 + r] + S1[pw * 16 + r];
            float t2 = S2[w * 16 + r] + S2[pw * 16 + r];
            mu[reg] = t1 * (1.0f / CC);
            float var = t2 * (1.0f / CC) - mu[reg] * mu[reg];
            rr[reg] = rsqrtf(var + 1e-5f);
        }
        #pragma unroll
        for (int nt = 0; nt < 4; nt++) {
            int col = nh * 64 + nt * 16 + r16;
            float wv = p.ln2_w[col], bv2 = p.ln2_b[col];
            #pragma unroll
            for (int reg = 0; reg < 4; reg++) {
                int lr = lr0 + quad * 4 + reg;
                ln2l[lr * 136 + col] = f2bf((x2r[nt][reg] - mu[reg]) * rr[reg] * wv + bv2);
            }
        }
        __syncthreads();   // ln2l ready (also xs dead beyond here)

        short8 af1[4];
        #pragma unroll
        for (int ks = 0; ks < 4; ks++)
            af1[ks] = *(const short8*)(ln2l + (lr0 + r16) * 136 + ks * 32 + quad * 8);
        #pragma unroll
        for (int g = 0; g < 4; g++) {
            floatx4 a2[4] = {};
            #pragma unroll
            for (int ks = 0; ks < 4; ks++) {
                #pragma unroll
                for (int nt = 0; nt < 4; nt++) {
                    int col = nh * 256 + g * 64 + nt * 16 + r16;
                    short8 bf = *(const short8*)(p.fc1T2 + ((size_t)(ks * 512 + col)) * 32 + quad * 8);
                    a2[nt] = __builtin_amdgcn_mfma_f32_16x16x32_bf16(af1[ks], bf, a2[nt], 0, 0, 0);
                }
            }
            #pragma unroll
            for (int nt = 0; nt < 4; nt++) {
                int col = nh * 256 + g * 64 + nt * 16 + r16;
                float bv = p.fc1_b[col];
                #pragma unroll
                for (int reg = 0; reg < 4; reg++) {
                    int lr = lr0 + quad * 4 + reg;
                    hl[lr * 520 + col] = f2bf(gelu_f(a2[nt][reg] + bv));
                }
            }
        }
        __syncthreads();   // hl ready

        floatx4 a3[4] = {};
        #pragma unroll
        for (int ks = 0; ks < 16; ks++) {
            short8 af = *(const short8*)(hl + (lr0 + r16) * 520 + ks * 32 + quad * 8);
            #pragma unroll
            for (int nt = 0; nt < 4; nt++) {
                int col = nh * 64 + nt * 16 + r16;
                short8 bf = *(const short8*)(p.fc2T2 + ((size_t)(ks * 128 + col)) * 32 + quad * 8);
                a3[nt] = __builtin_amdgcn_mfma_f32_16x16x32_bf16(af, bf, a3[nt], 0, 0, 0);
            }
        }
        __syncthreads();   // last reads of xs-region complete long ago; st overlay safe
        #pragma unroll
        for (int nt = 0; nt < 4; nt++) {
            int col = nh * 64 + nt * 16 + r16;
            float bv = p.fc2_b[col];
            #pragma unroll
            for (int reg = 0; reg < 4; reg++) {
                int lr = lr0 + quad * 4 + reg;
                st[col * 34 + lr] = a3[nt][reg] + bv + x2r[nt][reg];
            }
        }
        __syncthreads();
        {
            int col = t >> 1, ch = (t & 1) * 16;
            float* dst = p.out + (size_t)(n * CC + col) * HW + p0 + ch;
            #pragma unroll
            for (int u = 0; u < 4; u++) {
                float4 v;
                v.x = st[col * 34 + ch + u * 4 + 0];
                v.y = st[col * 34 + ch + u * 4 + 1];
                v.z = st[col * 34 + ch + u * 4 + 2];
                v.w = st[col * 34 + ch + u * 4 + 3];
                *(float4*)(dst + u * 4) = v;
            }
        }
    }
}

extern "C" void kernel_launch(void* const* d_in, const int* in_sizes, int n_in,
                              void* d_out, int out_size, void* d_ws, size_t ws_size,
                              hipStream_t stream)
{
    char* ws = (char*)d_ws;
    Params p;
    p.x       = (const float*)d_in[0];
    p.ln1_w   = (const float*)d_in[1];
    p.ln1_b   = (const float*)d_in[2];
    p.ln2_w   = (const float*)d_in[3];
    p.ln2_b   = (const float*)d_in[4];
    p.qkv_w   = (const float*)d_in[5];
    p.qkv_b   = (const float*)d_in[6];
    p.proj_w  = (const float*)d_in[7];
    p.proj_b  = (const float*)d_in[8];
    p.rpb     = (const float*)d_in[9];
    p.conv1_w = (const float*)d_in[10];
    p.conv1_b = (const float*)d_in[11];
    p.conv2_w = (const float*)d_in[12];
    p.conv2_b = (const float*)d_in[13];
    p.ca1_w   = (const float*)d_in[14];
    p.ca1_b   = (const float*)d_in[15];
    p.ca2_w   = (const float*)d_in[16];
    p.ca2_b   = (const float*)d_in[17];
    p.fc1_w   = (const float*)d_in[18];
    p.fc1_b   = (const float*)d_in[19];
    p.fc2_w   = (const float*)d_in[20];
    p.fc2_b   = (const float*)d_in[21];
    p.out     = (float*)d_out;

    p.xn     = (BF*)(ws);                  // M*128*2 = 4 MB
    p.qkv    = (BF*)(ws + 4194304);        // M*384*2 = 12 MB
    p.tbuf   = (BF*)(ws + 16777216);       // M*128*2 = 4 MB
    p.na     = (BF*)(ws + 20971520);       // M*128*2 = 4 MB
    p.part   = (float*)(ws + 25165824);    // 2 KB
    p.qkvT   = (BF*)(ws + 25167872);       // 98304 B
    p.c1T    = (BF*)(ws + 25266176);       // 8192 B
    p.c2T    = (BF*)(ws + 25274368);       // 8192 B
    p.projT2 = (BF*)(ws + 25282560);       // 32768 B
    p.fc1T2  = (BF*)(ws + 25315328);       // 131072 B
    p.fc2T2  = (BF*)(ws + 25446400);       // 131072 B

    void* args[] = { &p };
    hipLaunchCooperativeKernel((void*)mega_kernel, dim3(512), dim3(256),
                               args, 0, stream);
}

// Round 14
// 171.034 us; speedup vs baseline: 2.2666x; 2.2666x over previous
//
#include <hip/hip_runtime.h>
#include <hip/hip_bf16.h>
#include <math.h>

#define NB 4
#define CC 128
#define HH 64
#define WW 64
#define HEADS 4
#define KS 7
#define DD 32
#define HW 4096
#define MTOT 16384   // NB*HW

typedef unsigned short BF;
typedef short short8 __attribute__((ext_vector_type(8)));
typedef float floatx4 __attribute__((ext_vector_type(4)));

__device__ __forceinline__ float gelu_f(float x) {
    return 0.5f * x * (1.0f + erff(x * 0.70710678118654752440f));
}

__device__ __forceinline__ BF f2bf(float f) {
    union { float f; unsigned u; } a; a.f = f;
    unsigned u = a.u;
    unsigned r = u + 0x7FFFu + ((u >> 16) & 1u);   // RNE
    return (BF)(r >> 16);
}

__device__ __forceinline__ float bf2f(BF v) {
    return __uint_as_float(((unsigned)v) << 16);
}

#define LDK 40      // padded LDS row, K=32 tiles (bf16)
#define LDK128 136  // padded LDS row, K=128 tiles (bf16)

// ---------------- LN1 transpose-tile + one-time weight prep -----------
// blocks [0,512): LN1 NCHW -> bf16 NHWC rows
// blocks [512,640): weights -> bf16. qkv/c1/c2: [n][k]. proj/fc1/fc2:
// fragment-coalesced tiles [kstep][n][32]
__global__ __launch_bounds__(256) void ln1t_kernel(
    const float* __restrict__ x, const float* __restrict__ w,
    const float* __restrict__ b, BF* __restrict__ out,
    float* __restrict__ part,
    const float* __restrict__ qkv_w, const float* __restrict__ conv1_w,
    const float* __restrict__ conv2_w, const float* __restrict__ proj_w,
    const float* __restrict__ fc1_w, const float* __restrict__ fc2_w,
    BF* __restrict__ qkvT, BF* __restrict__ c1T, BF* __restrict__ c2T,
    BF* __restrict__ projT2, BF* __restrict__ fc1T2, BF* __restrict__ fc2T2)
{
    const int blk = blockIdx.x;
    const int t  = threadIdx.x;

    if (blk >= 512) {   // ---- weight prep (one-time, 204800 elems) ----
        for (int idx = (blk - 512) * 256 + t; idx < 204800; idx += 32768) {
            if (idx < 49152) {                    // qkvT [384][128]
                int l = idx, n = l >> 7, k = l & 127;
                qkvT[l] = f2bf(qkv_w[k * 384 + n]);
            } else if (idx < 53248) {             // c1T [32][128]
                int l = idx - 49152, n = l >> 7, k = l & 127;
                c1T[l] = f2bf(conv1_w[k * 32 + n]);
            } else if (idx < 57344) {             // c2T [128][32]
                int l = idx - 53248, n = l >> 5, k = l & 31;
                c2T[l] = f2bf(conv2_w[k * 128 + n]);
            } else if (idx < 73728) {             // projT2 [4][128][32]
                int l = idx - 57344, kk = l & 31, n = (l >> 5) & 127, ks = l >> 12;
                projT2[l] = f2bf(proj_w[(ks * 32 + kk) * 128 + n]);
            } else if (idx < 139264) {            // fc1T2 [4][512][32]
                int l = idx - 73728, kk = l & 31, n = (l >> 5) & 511, ks = l >> 14;
                fc1T2[l] = f2bf(fc1_w[(ks * 32 + kk) * 512 + n]);
            } else {                              // fc2T2 [16][128][32]
                int l = idx - 139264, kk = l & 31, n = (l >> 5) & 127, ks = l >> 12;
                fc2T2[l] = f2bf(fc2_w[(ks * 32 + kk) * 128 + n]);
            }
        }
        return;
    }

    __shared__ float xt[128][33];
    __shared__ float mus[32], rss[32];
    const int n  = blk >> 7;
    const int p0 = (blk & 127) * 32;
    if (blk < 4 && t < 128) part[blk * CC + t] = 0.f;   // zero CA partials

    {
        int pp = t & 31, c8 = t >> 5;
        #pragma unroll 4
        for (int it = 0; it < 16; it++) {
            int c = it * 8 + c8;
            xt[c][pp] = x[(size_t)(n * CC + c) * HW + p0 + pp];
        }
    }
    __syncthreads();
    {
        int pp2 = t >> 3, cb = t & 7;
        float s = 0.f;
        #pragma unroll
        for (int u = 0; u < 16; u++) s += xt[cb + u * 8][pp2];
        s += __shfl_xor(s, 1); s += __shfl_xor(s, 2); s += __shfl_xor(s, 4);
        float mu = s * (1.0f / CC);
        float v = 0.f;
        #pragma unroll
        for (int u = 0; u < 16; u++) { float d = xt[cb + u * 8][pp2] - mu; v += d * d; }
        v += __shfl_xor(v, 1); v += __shfl_xor(v, 2); v += __shfl_xor(v, 4);
        if (cb == 0) { mus[pp2] = mu; rss[pp2] = rsqrtf(v * (1.0f / CC) + 1e-5f); }
    }
    __syncthreads();
    {
        #pragma unroll
        for (int it = 0; it < 2; it++) {
            int pp2 = (t >> 4) + it * 16;
            int c0  = (t & 15) * 8;
            float mu = mus[pp2], rs = rss[pp2];
            int m = n * HW + p0 + pp2;
            short8 o;
            #pragma unroll
            for (int u = 0; u < 8; u++)
                o[u] = (short)f2bf((xt[c0 + u][pp2] - mu) * rs * w[c0 + u] + b[c0 + u]);
            *(short8*)(out + (size_t)m * CC + c0) = o;
        }
    }
}

// ---------------- phase2: qkv GEMM (2 row-tiles/block) + conv-MLP -----
// blocks [0,768): qkv — stage B once, compute rows row0 and row0+64
// blocks [768,1024): conv1+gelu+conv2 -> bf16 t + column sums
__global__ __launch_bounds__(256) void phase2(
    const BF* __restrict__ xn, const BF* __restrict__ qkvT,
    const float* __restrict__ qkv_b, BF* __restrict__ qkv_out,
    const BF* __restrict__ c1T, const float* __restrict__ b1,
    const BF* __restrict__ c2T, const float* __restrict__ b2,
    BF* __restrict__ tout, float* __restrict__ part)
{
    __shared__ __align__(16) char smem[26624];
    const int bid = blockIdx.x;
    const int t = threadIdx.x;
    const int w = t >> 6, lane = t & 63, q = lane >> 4, r16 = lane & 15;

    if (bid < 768) {
        BF* Bl = (BF*)smem;   // [64][LDK128]
        const int col0 = (bid % 6) * 64;
        const int row0 = (bid / 6) * 128;
        {   // stage 64 cols x 128 k bf16: 4 uint4 per thread
            int nn = t >> 2;
            int kk = (t & 3) * 32;
            const BF* src = qkvT + (size_t)(col0 + nn) * 128 + kk;
            #pragma unroll
            for (int u = 0; u < 4; u++)
                *(uint4*)(Bl + nn * LDK128 + kk + u * 8) = *(const uint4*)(src + u * 8);
        }
        __syncthreads();
        #pragma unroll
        for (int half = 0; half < 2; half++) {
            floatx4 acc[4] = {};
            const BF* arow = xn + (size_t)(row0 + half * 64 + w * 16 + r16) * CC;
            #pragma unroll
            for (int ks = 0; ks < 4; ks++) {
                short8 af = *(const short8*)(arow + ks * 32 + q * 8);
                #pragma unroll
                for (int nt = 0; nt < 4; nt++) {
                    short8 bf = *(const short8*)(Bl + (nt * 16 + r16) * LDK128 + ks * 32 + q * 8);
                    acc[nt] = __builtin_amdgcn_mfma_f32_16x16x32_bf16(af, bf, acc[nt], 0, 0, 0);
                }
            }
            #pragma unroll
            for (int nt = 0; nt < 4; nt++) {
                int col = col0 + nt * 16 + r16;
                float bv = qkv_b[col];
                #pragma unroll
                for (int reg = 0; reg < 4; reg++) {
                    int row = row0 + half * 64 + w * 16 + q * 4 + reg;
                    qkv_out[(size_t)row * 384 + col] = f2bf(acc[nt][reg] + bv);
                }
            }
        }
        return;
    }
    // ---- conv branch ----
    BF*    W1l = (BF*)smem;                  // [32][LDK128]  8704 B
    BF*    W2l = (BF*)(smem + 8704);         // [128][LDK]   10240 B
    BF*    Hl  = (BF*)(smem + 18944);        // [64][LDK]     5120 B
    float* red = (float*)(smem + 24064);     // [4][128]      2048 B
    const int row0 = (bid - 768) * 64;
    {
        #pragma unroll
        for (int it = 0; it < 2; it++) {
            int idx = it * 256 + t;
            int nn = idx >> 4, u = idx & 15;
            *(uint4*)(W1l + nn * LDK128 + u * 8) = *(const uint4*)(c1T + nn * 128 + u * 8);
        }
    }
    {
        #pragma unroll
        for (int it = 0; it < 2; it++) {
            int idx = it * 256 + t;
            int nn = idx >> 2, u = idx & 3;
            *(uint4*)(W2l + nn * LDK + u * 8) = *(const uint4*)(c2T + nn * 32 + u * 8);
        }
    }
    __syncthreads();
    floatx4 a1[2] = {};
    const BF* arow = xn + (size_t)(row0 + w * 16 + r16) * CC;
    #pragma unroll
    for (int ks = 0; ks < 4; ks++) {
        short8 af = *(const short8*)(arow + ks * 32 + q * 8);
        #pragma unroll
        for (int nt = 0; nt < 2; nt++) {
            short8 bf = *(const short8*)(W1l + (nt * 16 + r16) * LDK128 + ks * 32 + q * 8);
            a1[nt] = __builtin_amdgcn_mfma_f32_16x16x32_bf16(af, bf, a1[nt], 0, 0, 0);
        }
    }
    #pragma unroll
    for (int nt = 0; nt < 2; nt++) {
        int col = nt * 16 + r16;
        float bv = b1[col];
        #pragma unroll
        for (int reg = 0; reg < 4; reg++)
            Hl[(w * 16 + q * 4 + reg) * LDK + col] = f2bf(gelu_f(a1[nt][reg] + bv));
    }
    __syncthreads();
    floatx4 a2[8] = {};
    short8 af2 = *(const short8*)(Hl + (w * 16 + r16) * LDK + q * 8);
    #pragma unroll
    for (int nt = 0; nt < 8; nt++) {
        short8 bf = *(const short8*)(W2l + (nt * 16 + r16) * LDK + q * 8);
        a2[nt] = __builtin_amdgcn_mfma_f32_16x16x32_bf16(af2, bf, a2[nt], 0, 0, 0);
    }
    #pragma unroll
    for (int nt = 0; nt < 8; nt++) {
        int col = nt * 16 + r16;
        float bv = b2[col];
        float s = 0.f;
        #pragma unroll
        for (int reg = 0; reg < 4; reg++) {
            int row = row0 + w * 16 + q * 4 + reg;
            float v = a2[nt][reg] + bv;
            tout[(size_t)row * CC + col] = f2bf(v);
            s += v;
        }
        s += __shfl_xor(s, 16);
        s += __shfl_xor(s, 32);
        if (lane < 16) red[w * 128 + col] = s;
    }
    __syncthreads();
    if (t < 128) {
        float cs = red[t] + red[128 + t] + red[256 + t] + red[384 + t];
        atomicAdd(&part[(row0 >> 12) * CC + t], cs);
    }
}

// ---------------- MFMA neighborhood attention (unchanged) -------------
__global__ __launch_bounds__(256) void na_mfma_kernel(
    const BF* __restrict__ qkv, const float* __restrict__ rpb,
    BF* __restrict__ outp)
{
    __shared__ __align__(16) BF Kt[224][40];
    __shared__ __align__(16) BF Vt[32][232];
    __shared__ __align__(16) BF Qb[64][40];
    __shared__ __align__(16) BF Pl[4][16][232];
    __shared__ float rb[169];

    const int b = blockIdx.x;
    const int h = b & 3;
    const int tile = b >> 2;
    const int n = tile >> 6;
    const int ti = (tile >> 3) & 7, tj = tile & 7;
    const int t = threadIdx.x;
    const int w = t >> 6, lane = t & 63, quad = lane >> 4, r16 = lane & 15;
    const int i0 = ti * 8, j0 = tj * 8;
    const int wi0 = max(i0 - 3, 0), wj0 = max(j0 - 3, 0);
    const int R  = min(wi0 + 13, 63) - wi0 + 1;
    const int Rj = min(wj0 + 13, 63) - wj0 + 1;

    for (int idx = t; idx < 896; idx += 256) {
        int key = idx >> 2, ch = idx & 3;
        int kr = key >> 4, kc = key & 15;
        uint4 v = {0u, 0u, 0u, 0u};
        if (kr < R && kc < Rj) {
            size_t pix = (size_t)((n * HH + wi0 + kr) * WW + wj0 + kc);
            v = *(const uint4*)(qkv + pix * 384 + 128 + h * DD + ch * 8);
        }
        *(uint4*)&Kt[key][ch * 8] = v;
    }
    for (int idx = t; idx < 896; idx += 256) {
        int key = idx >> 2, ch = idx & 3;
        int kr = key >> 4, kc = key & 15;
        if (kr < R && kc < Rj) {
            size_t pix = (size_t)((n * HH + wi0 + kr) * WW + wj0 + kc);
            uint4 v = *(const uint4*)(qkv + pix * 384 + 256 + h * DD + ch * 8);
            const BF* pv = (const BF*)&v;
            #pragma unroll
            for (int u = 0; u < 8; u++) Vt[ch * 8 + u][key] = pv[u];
        } else {
            #pragma unroll
            for (int u = 0; u < 8; u++) Vt[ch * 8 + u][key] = 0;
        }
    }
    {
        int q = t >> 2, ch = t & 3;
        size_t mq = (size_t)((n * HH + i0 + (q >> 3)) * WW + j0 + (q & 7));
        *(uint4*)&Qb[q][ch * 8] = *(const uint4*)(qkv + mq * 384 + h * DD + ch * 8);
    }
    if (t < 169) rb[t] = rpb[h * 169 + t];
    __syncthreads();

    int oi[4], cok[4], bj0[4], ai_[4];
    #pragma unroll
    for (int reg = 0; reg < 4; reg++) {
        int q = w * 16 + quad * 4 + reg;
        int i = i0 + (q >> 3), j = j0 + (q & 7);
        int ni = min(max(i - 3, 0), HH - KS), nj = min(max(j - 3, 0), WW - KS);
        oi[reg]  = ni - wi0;
        ai_[reg] = ni - i + 6;
        int dc = r16 - (nj - wj0);
        cok[reg] = ((unsigned)dc < 7u) ? 1 : 0;
        bj0[reg] = min(max(dc + (nj - j + 6), 0), 12);
    }

    short8 aq = *(const short8*)&Qb[w * 16 + r16][quad * 8];
    floatx4 S[14];
    #pragma unroll
    for (int nt = 0; nt < 14; nt++) {
        floatx4 z = {0.f, 0.f, 0.f, 0.f};
        short8 bk = *(const short8*)&Kt[nt * 16 + r16][quad * 8];
        S[nt] = __builtin_amdgcn_mfma_f32_16x16x32_bf16(aq, bk, z, 0, 0, 0);
    }
    const float scale = 0.17677669529663688110f;
    #pragma unroll
    for (int nt = 0; nt < 14; nt++) {
        #pragma unroll
        for (int reg = 0; reg < 4; reg++) {
            int dr = nt - oi[reg];
            bool ok = ((unsigned)dr < 7u) && cok[reg];
            int bi = min(max(dr + ai_[reg], 0), 12);
            float bias = rb[bi * 13 + bj0[reg]];
            S[nt][reg] = ok ? fmaf(S[nt][reg], scale, bias) : -1e30f;
        }
    }
    float rinv[4];
    #pragma unroll
    for (int reg = 0; reg < 4; reg++) {
        float m = S[0][reg];
        #pragma unroll
        for (int nt = 1; nt < 14; nt++) m = fmaxf(m, S[nt][reg]);
        m = fmaxf(m, __shfl_xor(m, 1));
        m = fmaxf(m, __shfl_xor(m, 2));
        m = fmaxf(m, __shfl_xor(m, 4));
        m = fmaxf(m, __shfl_xor(m, 8));
        float s = 0.f;
        #pragma unroll
        for (int nt = 0; nt < 14; nt++) {
            float e = __expf(S[nt][reg] - m);
            S[nt][reg] = e;
            s += e;
        }
        s += __shfl_xor(s, 1);
        s += __shfl_xor(s, 2);
        s += __shfl_xor(s, 4);
        s += __shfl_xor(s, 8);
        rinv[reg] = 1.0f / s;
    }
    #pragma unroll
    for (int nt = 0; nt < 14; nt++)
        #pragma unroll
        for (int reg = 0; reg < 4; reg++)
            Pl[w][quad * 4 + reg][nt * 16 + r16] = f2bf(S[nt][reg] * rinv[reg]);

    floatx4 O0 = {0.f, 0.f, 0.f, 0.f}, O1 = {0.f, 0.f, 0.f, 0.f};
    #pragma unroll
    for (int ks = 0; ks < 7; ks++) {
        short8 ap = *(const short8*)&Pl[w][r16][ks * 32 + quad * 8];
        short8 b0 = *(const short8*)&Vt[r16][ks * 32 + quad * 8];
        short8 b1 = *(const short8*)&Vt[16 + r16][ks * 32 + quad * 8];
        O0 = __builtin_amdgcn_mfma_f32_16x16x32_bf16(ap, b0, O0, 0, 0, 0);
        O1 = __builtin_amdgcn_mfma_f32_16x16x32_bf16(ap, b1, O1, 0, 0, 0);
    }
    #pragma unroll
    for (int reg = 0; reg < 4; reg++) {
        int q = w * 16 + quad * 4 + reg;
        size_t m = (size_t)((n * HH + i0 + (q >> 3)) * WW + j0 + (q & 7));
        outp[m * CC + h * DD + r16]      = f2bf(O0[reg]);
        outp[m * CC + h * DD + 16 + r16] = f2bf(O1[reg]);
    }
}

// ---------------- fused tail: proj + gate + x2 + LN2 + fc1 + fc2 ------
__global__ __launch_bounds__(256) void tail_kernel(
    const BF* __restrict__ A, const BF* __restrict__ projT2,
    const float* __restrict__ proj_b, const float* __restrict__ x,
    const BF* __restrict__ tbuf, const float* __restrict__ part,
    const float* __restrict__ ca1_w, const float* __restrict__ ca1_b,
    const float* __restrict__ ca2_w, const float* __restrict__ ca2_b,
    const float* __restrict__ w2, const float* __restrict__ b2,
    const BF* __restrict__ fc1T2, const float* __restrict__ fc1_b,
    const BF* __restrict__ fc2T2, const float* __restrict__ fc2_b,
    float* __restrict__ out)
{
    __shared__ float xs[32][132];            // 16896 B  x tile [p][c]
    __shared__ __align__(16) BF ln2l[32][136];  // 8704 B
    __shared__ __align__(16) BF hl[32][520];    // 33280 B  fc1 out
    __shared__ float st[128][34];            // 17408 B  store tile [c][p]
    __shared__ float gs[128], h1s[7], gl[128];
    __shared__ float S1[4][16], S2[4][16];

    const int t = threadIdx.x;
    const int w = t >> 6, lane = t & 63, quad = lane >> 4, r16 = lane & 15;
    const int row0 = blockIdx.x * 32;
    const int n = row0 >> 12, p0 = row0 & 4095;
    const int mt = w & 1, nh = w >> 1;
    const int lr0 = mt * 16;

    #pragma unroll
    for (int it = 0; it < 4; it++) {
        int idx4 = it * 256 + t;
        int p4 = idx4 & 7, c = idx4 >> 3;
        float4 v = *(const float4*)(x + (size_t)(n * CC + c) * HW + p0 + p4 * 4);
        xs[p4 * 4 + 0][c] = v.x; xs[p4 * 4 + 1][c] = v.y;
        xs[p4 * 4 + 2][c] = v.z; xs[p4 * 4 + 3][c] = v.w;
    }
    if (t < 128) gs[t] = part[n * CC + t] * (1.0f / HW);
    __syncthreads();
    if (t < 7) {
        float a = ca1_b[t];
        for (int k = 0; k < 128; k++) a += gs[k] * ca1_w[k * 7 + t];
        h1s[t] = fmaxf(a, 0.f);
    }
    __syncthreads();
    if (t < 128) {
        float o = ca2_b[t];
        #pragma unroll
        for (int r = 0; r < 7; r++) o += h1s[r] * ca2_w[r * 128 + t];
        gl[t] = 1.0f / (1.0f + expf(-o));
    }

    floatx4 acc[4] = {};
    const BF* arow = A + (size_t)(row0 + lr0 + r16) * CC;
    #pragma unroll
    for (int ks = 0; ks < 4; ks++) {
        short8 af = *(const short8*)(arow + ks * 32 + quad * 8);
        #pragma unroll
        for (int nt = 0; nt < 4; nt++) {
            int col = nh * 64 + nt * 16 + r16;
            short8 bf = *(const short8*)(projT2 + ((size_t)(ks * 128 + col)) * 32 + quad * 8);
            acc[nt] = __builtin_amdgcn_mfma_f32_16x16x32_bf16(af, bf, acc[nt], 0, 0, 0);
        }
    }
    __syncthreads();   // gl ready

    float x2r[4][4];
    float s1[4] = {0.f, 0.f, 0.f, 0.f}, s2[4] = {0.f, 0.f, 0.f, 0.f};
    #pragma unroll
    for (int nt = 0; nt < 4; nt++) {
        int col = nh * 64 + nt * 16 + r16;
        float bv = proj_b[col], gv = gl[col];
        #pragma unroll
        for (int reg = 0; reg < 4; reg++) {
            int lr = lr0 + quad * 4 + reg;
            float tv = bf2f(tbuf[(size_t)(row0 + lr) * CC + col]);
            float v = acc[nt][reg] + bv + xs[lr][col] + 0.02f * tv * gv;
            x2r[nt][reg] = v;
            s1[reg] += v; s2[reg] += v * v;
        }
    }
    #pragma unroll
    for (int reg = 0; reg < 4; reg++) {
        #pragma unroll
        for (int off = 8; off; off >>= 1) {
            s1[reg] += __shfl_xor(s1[reg], off);
            s2[reg] += __shfl_xor(s2[reg], off);
        }
    }
    if (r16 == 0) {
        #pragma unroll
        for (int reg = 0; reg < 4; reg++) {
            S1[w][quad * 4 + reg] = s1[reg];
            S2[w][quad * 4 + reg] = s2[reg];
        }
    }
    __syncthreads();
    const int pw = w ^ 2;
    float mu[4], rr[4];
    #pragma unroll
    for (int reg = 0; reg < 4; reg++) {
        int r = quad * 4 + reg;
        float t1 = S1[w][r] + S1[pw][r];
        float t2 = S2[w][r] + S2[pw][r];
        mu[reg] = t1 * (1.0f / CC);
        float var = t2 * (1.0f / CC) - mu[reg] * mu[reg];
        rr[reg] = rsqrtf(var + 1e-5f);
    }
    #pragma unroll
    for (int nt = 0; nt < 4; nt++) {
        int col = nh * 64 + nt * 16 + r16;
        float wv = w2[col], bv2 = b2[col];
        #pragma unroll
        for (int reg = 0; reg < 4; reg++) {
            int lr = lr0 + quad * 4 + reg;
            ln2l[lr][col] = f2bf((x2r[nt][reg] - mu[reg]) * rr[reg] * wv + bv2);
        }
    }
    __syncthreads();   // ln2l ready

    short8 af1[4];
    #pragma unroll
    for (int ks = 0; ks < 4; ks++)
        af1[ks] = *(const short8*)&ln2l[lr0 + r16][ks * 32 + quad * 8];
    #pragma unroll
    for (int g = 0; g < 4; g++) {
        floatx4 a2[4] = {};
        #pragma unroll
        for (int ks = 0; ks < 4; ks++) {
            #pragma unroll
            for (int nt = 0; nt < 4; nt++) {
                int col = nh * 256 + g * 64 + nt * 16 + r16;
                short8 bf = *(const short8*)(fc1T2 + ((size_t)(ks * 512 + col)) * 32 + quad * 8);
                a2[nt] = __builtin_amdgcn_mfma_f32_16x16x32_bf16(af1[ks], bf, a2[nt], 0, 0, 0);
            }
        }
        #pragma unroll
        for (int nt = 0; nt < 4; nt++) {
            int col = nh * 256 + g * 64 + nt * 16 + r16;
            float bv = fc1_b[col];
            #pragma unroll
            for (int reg = 0; reg < 4; reg++) {
                int lr = lr0 + quad * 4 + reg;
                hl[lr][col] = f2bf(gelu_f(a2[nt][reg] + bv));
            }
        }
    }
    __syncthreads();   // hl ready

    floatx4 a3[4] = {};
    #pragma unroll
    for (int ks = 0; ks < 16; ks++) {
        short8 af = *(const short8*)&hl[lr0 + r16][ks * 32 + quad * 8];
        #pragma unroll
        for (int nt = 0; nt < 4; nt++) {
            int col = nh * 64 + nt * 16 + r16;
            short8 bf = *(const short8*)(fc2T2 + ((size_t)(ks * 128 + col)) * 32 + quad * 8);
            a3[nt] = __builtin_amdgcn_mfma_f32_16x16x32_bf16(af, bf, a3[nt], 0, 0, 0);
        }
    }
    #pragma unroll
    for (int nt = 0; nt < 4; nt++) {
        int col = nh * 64 + nt * 16 + r16;
        float bv = fc2_b[col];
        #pragma unroll
        for (int reg = 0; reg < 4; reg++) {
            int lr = lr0 + quad * 4 + reg;
            st[col][lr] = a3[nt][reg] + bv + x2r[nt][reg];
        }
    }
    __syncthreads();
    {
        int col = t >> 1, ch = (t & 1) * 16;
        float* dst = out + (size_t)(n * CC + col) * HW + p0 + ch;
        #pragma unroll
        for (int u = 0; u < 4; u++) {
            float4 v;
            v.x = st[col][ch + u * 4 + 0];
            v.y = st[col][ch + u * 4 + 1];
            v.z = st[col][ch + u * 4 + 2];
            v.w = st[col][ch + u * 4 + 3];
            *(float4*)(dst + u * 4) = v;
        }
    }
}

extern "C" void kernel_launch(void* const* d_in, const int* in_sizes, int n_in,
                              void* d_out, int out_size, void* d_ws, size_t ws_size,
                              hipStream_t stream)
{
    const float* x       = (const float*)d_in[0];
    const float* ln1_w   = (const float*)d_in[1];
    const float* ln1_b   = (const float*)d_in[2];
    const float* ln2_w   = (const float*)d_in[3];
    const float* ln2_b   = (const float*)d_in[4];
    const float* qkv_w   = (const float*)d_in[5];
    const float* qkv_b   = (const float*)d_in[6];
    const float* proj_w  = (const float*)d_in[7];
    const float* proj_b  = (const float*)d_in[8];
    const float* rpb     = (const float*)d_in[9];
    const float* conv1_w = (const float*)d_in[10];
    const float* conv1_b = (const float*)d_in[11];
    const float* conv2_w = (const float*)d_in[12];
    const float* conv2_b = (const float*)d_in[13];
    const float* ca1_w   = (const float*)d_in[14];
    const float* ca1_b   = (const float*)d_in[15];
    const float* ca2_w   = (const float*)d_in[16];
    const float* ca2_b   = (const float*)d_in[17];
    const float* fc1_w   = (const float*)d_in[18];
    const float* fc1_b   = (const float*)d_in[19];
    const float* fc2_w   = (const float*)d_in[20];
    const float* fc2_b   = (const float*)d_in[21];
    float* out = (float*)d_out;

    char* ws = (char*)d_ws;
    BF*    xn_bf   = (BF*)(ws);                  // M*128*2 = 4 MB
    BF*    qkv_bf  = (BF*)(ws + 4194304);        // M*384*2 = 12 MB
    BF*    t_bf    = (BF*)(ws + 16777216);       // M*128*2 = 4 MB
    BF*    na_bf   = (BF*)(ws + 20971520);       // M*128*2 = 4 MB
    float* part    = (float*)(ws + 25165824);    // 2 KB
    BF*    qkvT    = (BF*)(ws + 25167872);       // 98304 B
    BF*    c1T     = (BF*)(ws + 25266176);       // 8192 B
    BF*    c2T     = (BF*)(ws + 25274368);       // 8192 B
    BF*    projT2  = (BF*)(ws + 25282560);       // 32768 B
    BF*    fc1T2   = (BF*)(ws + 25315328);       // 131072 B
    BF*    fc2T2   = (BF*)(ws + 25446400);       // 131072 B

    // 1. LN1 transpose-tile + one-time weight prep (blocks 512..639)
    ln1t_kernel<<<640, 256, 0, stream>>>(x, ln1_w, ln1_b, xn_bf, part,
        qkv_w, conv1_w, conv2_w, proj_w, fc1_w, fc2_w,
        qkvT, c1T, c2T, projT2, fc1T2, fc2T2);
    // 2. qkv GEMM (2 row-tiles/block) + conv-MLP, one launch
    phase2<<<1024, 256, 0, stream>>>(xn_bf, qkvT, qkv_b, qkv_bf,
                                     c1T, conv1_b, c2T, conv2_b, t_bf, part);
    // 3. MFMA neighborhood attention
    na_mfma_kernel<<<1024, 256, 0, stream>>>(qkv_bf, rpb, na_bf);
    // 4. fused tail: CA gate + proj + x2 + LN2 + fc1 + fc2 + NCHW store
    tail_kernel<<<512, 256, 0, stream>>>(na_bf, projT2, proj_b, x, t_bf, part,
                                         ca1_w, ca1_b, ca2_w, ca2_b,
                                         ln2_w, ln2_b, fc1T2, fc1_b,
                                         fc2T2, fc2_b, out);
}

// Round 15
// 162.765 us; speedup vs baseline: 2.3818x; 1.0508x over previous
//
#include <hip/hip_runtime.h>
#include <hip/hip_bf16.h>
#include <math.h>

#define NB 4
#define CC 128
#define HH 64
#define WW 64
#define HEADS 4
#define KS 7
#define DD 32
#define HW 4096
#define MTOT 16384   // NB*HW

typedef unsigned short BF;
typedef short short8 __attribute__((ext_vector_type(8)));
typedef float floatx4 __attribute__((ext_vector_type(4)));

__device__ __forceinline__ float gelu_f(float x) {
    return 0.5f * x * (1.0f + erff(x * 0.70710678118654752440f));
}

__device__ __forceinline__ BF f2bf(float f) {
    union { float f; unsigned u; } a; a.f = f;
    unsigned u = a.u;
    unsigned r = u + 0x7FFFu + ((u >> 16) & 1u);   // RNE
    return (BF)(r >> 16);
}

__device__ __forceinline__ float bf2f(BF v) {
    return __uint_as_float(((unsigned)v) << 16);
}

#define LDK 40      // padded LDS row, K=32 tiles (bf16)
#define LDK128 136  // padded LDS row, K=128 tiles (bf16)

// ---------------- LN1 transpose-tile + one-time weight prep -----------
__global__ __launch_bounds__(256) void ln1t_kernel(
    const float* __restrict__ x, const float* __restrict__ w,
    const float* __restrict__ b, BF* __restrict__ out,
    float* __restrict__ part,
    const float* __restrict__ qkv_w, const float* __restrict__ conv1_w,
    const float* __restrict__ conv2_w, const float* __restrict__ proj_w,
    const float* __restrict__ fc1_w, const float* __restrict__ fc2_w,
    BF* __restrict__ qkvT, BF* __restrict__ c1T, BF* __restrict__ c2T,
    BF* __restrict__ projT2, BF* __restrict__ fc1T2, BF* __restrict__ fc2T2)
{
    const int blk = blockIdx.x;
    const int t  = threadIdx.x;

    if (blk >= 512) {   // ---- weight prep (one-time, 204800 elems) ----
        for (int idx = (blk - 512) * 256 + t; idx < 204800; idx += 32768) {
            if (idx < 49152) {                    // qkvT [384][128]
                int l = idx, n = l >> 7, k = l & 127;
                qkvT[l] = f2bf(qkv_w[k * 384 + n]);
            } else if (idx < 53248) {             // c1T [32][128]
                int l = idx - 49152, n = l >> 7, k = l & 127;
                c1T[l] = f2bf(conv1_w[k * 32 + n]);
            } else if (idx < 57344) {             // c2T [128][32]
                int l = idx - 53248, n = l >> 5, k = l & 31;
                c2T[l] = f2bf(conv2_w[k * 128 + n]);
            } else if (idx < 73728) {             // projT2 [4][128][32]
                int l = idx - 57344, kk = l & 31, n = (l >> 5) & 127, ks = l >> 12;
                projT2[l] = f2bf(proj_w[(ks * 32 + kk) * 128 + n]);
            } else if (idx < 139264) {            // fc1T2 [4][512][32]
                int l = idx - 73728, kk = l & 31, n = (l >> 5) & 511, ks = l >> 14;
                fc1T2[l] = f2bf(fc1_w[(ks * 32 + kk) * 512 + n]);
            } else {                              // fc2T2 [16][128][32]
                int l = idx - 139264, kk = l & 31, n = (l >> 5) & 127, ks = l >> 12;
                fc2T2[l] = f2bf(fc2_w[(ks * 32 + kk) * 128 + n]);
            }
        }
        return;
    }

    __shared__ float xt[128][33];
    __shared__ float mus[32], rss[32];
    const int n  = blk >> 7;
    const int p0 = (blk & 127) * 32;
    if (blk < 4 && t < 128) part[blk * CC + t] = 0.f;   // zero CA partials

    {
        int pp = t & 31, c8 = t >> 5;
        #pragma unroll 4
        for (int it = 0; it < 16; it++) {
            int c = it * 8 + c8;
            xt[c][pp] = x[(size_t)(n * CC + c) * HW + p0 + pp];
        }
    }
    __syncthreads();
    {
        int pp2 = t >> 3, cb = t & 7;
        float s = 0.f;
        #pragma unroll
        for (int u = 0; u < 16; u++) s += xt[cb + u * 8][pp2];
        s += __shfl_xor(s, 1); s += __shfl_xor(s, 2); s += __shfl_xor(s, 4);
        float mu = s * (1.0f / CC);
        float v = 0.f;
        #pragma unroll
        for (int u = 0; u < 16; u++) { float d = xt[cb + u * 8][pp2] - mu; v += d * d; }
        v += __shfl_xor(v, 1); v += __shfl_xor(v, 2); v += __shfl_xor(v, 4);
        if (cb == 0) { mus[pp2] = mu; rss[pp2] = rsqrtf(v * (1.0f / CC) + 1e-5f); }
    }
    __syncthreads();
    {
        #pragma unroll
        for (int it = 0; it < 2; it++) {
            int pp2 = (t >> 4) + it * 16;
            int c0  = (t & 15) * 8;
            float mu = mus[pp2], rs = rss[pp2];
            int m = n * HW + p0 + pp2;
            short8 o;
            #pragma unroll
            for (int u = 0; u < 8; u++)
                o[u] = (short)f2bf((xt[c0 + u][pp2] - mu) * rs * w[c0 + u] + b[c0 + u]);
            *(short8*)(out + (size_t)m * CC + c0) = o;
        }
    }
}

// ---------------- phase2: qkv GEMM (2 row-tiles/block) + conv-MLP -----
__global__ __launch_bounds__(256) void phase2(
    const BF* __restrict__ xn, const BF* __restrict__ qkvT,
    const float* __restrict__ qkv_b, BF* __restrict__ qkv_out,
    const BF* __restrict__ c1T, const float* __restrict__ b1,
    const BF* __restrict__ c2T, const float* __restrict__ b2,
    BF* __restrict__ tout, float* __restrict__ part)
{
    __shared__ __align__(16) char smem[26624];
    const int bid = blockIdx.x;
    const int t = threadIdx.x;
    const int w = t >> 6, lane = t & 63, q = lane >> 4, r16 = lane & 15;

    if (bid < 768) {
        BF* Bl = (BF*)smem;   // [64][LDK128]
        const int col0 = (bid % 6) * 64;
        const int row0 = (bid / 6) * 128;
        {
            int nn = t >> 2;
            int kk = (t & 3) * 32;
            const BF* src = qkvT + (size_t)(col0 + nn) * 128 + kk;
            #pragma unroll
            for (int u = 0; u < 4; u++)
                *(uint4*)(Bl + nn * LDK128 + kk + u * 8) = *(const uint4*)(src + u * 8);
        }
        __syncthreads();
        #pragma unroll
        for (int half = 0; half < 2; half++) {
            floatx4 acc[4] = {};
            const BF* arow = xn + (size_t)(row0 + half * 64 + w * 16 + r16) * CC;
            #pragma unroll
            for (int ks = 0; ks < 4; ks++) {
                short8 af = *(const short8*)(arow + ks * 32 + q * 8);
                #pragma unroll
                for (int nt = 0; nt < 4; nt++) {
                    short8 bf = *(const short8*)(Bl + (nt * 16 + r16) * LDK128 + ks * 32 + q * 8);
                    acc[nt] = __builtin_amdgcn_mfma_f32_16x16x32_bf16(af, bf, acc[nt], 0, 0, 0);
                }
            }
            #pragma unroll
            for (int nt = 0; nt < 4; nt++) {
                int col = col0 + nt * 16 + r16;
                float bv = qkv_b[col];
                #pragma unroll
                for (int reg = 0; reg < 4; reg++) {
                    int row = row0 + half * 64 + w * 16 + q * 4 + reg;
                    qkv_out[(size_t)row * 384 + col] = f2bf(acc[nt][reg] + bv);
                }
            }
        }
        return;
    }
    // ---- conv branch ----
    BF*    W1l = (BF*)smem;                  // [32][LDK128]  8704 B
    BF*    W2l = (BF*)(smem + 8704);         // [128][LDK]   10240 B
    BF*    Hl  = (BF*)(smem + 18944);        // [64][LDK]     5120 B
    float* red = (float*)(smem + 24064);     // [4][128]      2048 B
    const int row0 = (bid - 768) * 64;
    {
        #pragma unroll
        for (int it = 0; it < 2; it++) {
            int idx = it * 256 + t;
            int nn = idx >> 4, u = idx & 15;
            *(uint4*)(W1l + nn * LDK128 + u * 8) = *(const uint4*)(c1T + nn * 128 + u * 8);
        }
    }
    {
        #pragma unroll
        for (int it = 0; it < 2; it++) {
            int idx = it * 256 + t;
            int nn = idx >> 2, u = idx & 3;
            *(uint4*)(W2l + nn * LDK + u * 8) = *(const uint4*)(c2T + nn * 32 + u * 8);
        }
    }
    __syncthreads();
    floatx4 a1[2] = {};
    const BF* arow = xn + (size_t)(row0 + w * 16 + r16) * CC;
    #pragma unroll
    for (int ks = 0; ks < 4; ks++) {
        short8 af = *(const short8*)(arow + ks * 32 + q * 8);
        #pragma unroll
        for (int nt = 0; nt < 2; nt++) {
            short8 bf = *(const short8*)(W1l + (nt * 16 + r16) * LDK128 + ks * 32 + q * 8);
            a1[nt] = __builtin_amdgcn_mfma_f32_16x16x32_bf16(af, bf, a1[nt], 0, 0, 0);
        }
    }
    #pragma unroll
    for (int nt = 0; nt < 2; nt++) {
        int col = nt * 16 + r16;
        float bv = b1[col];
        #pragma unroll
        for (int reg = 0; reg < 4; reg++)
            Hl[(w * 16 + q * 4 + reg) * LDK + col] = f2bf(gelu_f(a1[nt][reg] + bv));
    }
    __syncthreads();
    floatx4 a2[8] = {};
    short8 af2 = *(const short8*)(Hl + (w * 16 + r16) * LDK + q * 8);
    #pragma unroll
    for (int nt = 0; nt < 8; nt++) {
        short8 bf = *(const short8*)(W2l + (nt * 16 + r16) * LDK + q * 8);
        a2[nt] = __builtin_amdgcn_mfma_f32_16x16x32_bf16(af2, bf, a2[nt], 0, 0, 0);
    }
    #pragma unroll
    for (int nt = 0; nt < 8; nt++) {
        int col = nt * 16 + r16;
        float bv = b2[col];
        float s = 0.f;
        #pragma unroll
        for (int reg = 0; reg < 4; reg++) {
            int row = row0 + w * 16 + q * 4 + reg;
            float v = a2[nt][reg] + bv;
            tout[(size_t)row * CC + col] = f2bf(v);
            s += v;
        }
        s += __shfl_xor(s, 16);
        s += __shfl_xor(s, 32);
        if (lane < 16) red[w * 128 + col] = s;
    }
    __syncthreads();
    if (t < 128) {
        float cs = red[t] + red[128 + t] + red[256 + t] + red[384 + t];
        atomicAdd(&part[(row0 >> 12) * CC + t], cs);
    }
}

// ---------------- MFMA neighborhood attention (tile-pruned) -----------
// Per wave: its 16 queries span pixel rows {i0+2w, i0+2w+1}; only key-grid
// rows kt0..kt0+7 can be valid (kt0 from first row). Score: 8 MFMAs.
// PV: 4 (kt0 even) or 5 (odd) 32-key chunks; odd kt0 zeroes 2 boundary
// P-tiles. Arithmetic identical to the 14-tile version (pruned P == 0).
__global__ __launch_bounds__(256) void na_mfma_kernel(
    const BF* __restrict__ qkv, const float* __restrict__ rpb,
    BF* __restrict__ outp)
{
    __shared__ __align__(16) BF Kt[224][40];
    __shared__ __align__(16) BF Vt[32][232];
    __shared__ __align__(16) BF Qb[64][40];
    __shared__ __align__(16) BF Pl[4][16][232];
    __shared__ float rb[169];

    const int b = blockIdx.x;
    const int h = b & 3;
    const int tile = b >> 2;
    const int n = tile >> 6;
    const int ti = (tile >> 3) & 7, tj = tile & 7;
    const int t = threadIdx.x;
    const int w = t >> 6, lane = t & 63, quad = lane >> 4, r16 = lane & 15;
    const int i0 = ti * 8, j0 = tj * 8;
    const int wi0 = max(i0 - 3, 0), wj0 = max(j0 - 3, 0);
    const int R  = min(wi0 + 13, 63) - wi0 + 1;
    const int Rj = min(wj0 + 13, 63) - wj0 + 1;

    for (int idx = t; idx < 896; idx += 256) {
        int key = idx >> 2, ch = idx & 3;
        int kr = key >> 4, kc = key & 15;
        uint4 v = {0u, 0u, 0u, 0u};
        if (kr < R && kc < Rj) {
            size_t pix = (size_t)((n * HH + wi0 + kr) * WW + wj0 + kc);
            v = *(const uint4*)(qkv + pix * 384 + 128 + h * DD + ch * 8);
        }
        *(uint4*)&Kt[key][ch * 8] = v;
    }
    for (int idx = t; idx < 896; idx += 256) {
        int key = idx >> 2, ch = idx & 3;
        int kr = key >> 4, kc = key & 15;
        if (kr < R && kc < Rj) {
            size_t pix = (size_t)((n * HH + wi0 + kr) * WW + wj0 + kc);
            uint4 v = *(const uint4*)(qkv + pix * 384 + 256 + h * DD + ch * 8);
            const BF* pv = (const BF*)&v;
            #pragma unroll
            for (int u = 0; u < 8; u++) Vt[ch * 8 + u][key] = pv[u];
        } else {
            #pragma unroll
            for (int u = 0; u < 8; u++) Vt[ch * 8 + u][key] = 0;
        }
    }
    {
        int q = t >> 2, ch = t & 3;
        size_t mq = (size_t)((n * HH + i0 + (q >> 3)) * WW + j0 + (q & 7));
        *(uint4*)&Qb[q][ch * 8] = *(const uint4*)(qkv + mq * 384 + h * DD + ch * 8);
    }
    if (t < 169) rb[t] = rpb[h * 169 + t];
    __syncthreads();

    // wave's first pixel row -> pruned k-tile base
    const int kt0 = min(max(i0 + 2 * w - 3, 0), HH - KS) - wi0;

    int oi[4], cok[4], bj0[4], ai_[4];
    #pragma unroll
    for (int reg = 0; reg < 4; reg++) {
        int q = w * 16 + quad * 4 + reg;
        int i = i0 + (q >> 3), j = j0 + (q & 7);
        int ni = min(max(i - 3, 0), HH - KS), nj = min(max(j - 3, 0), WW - KS);
        oi[reg]  = ni - wi0;
        ai_[reg] = ni - i + 6;
        int dc = r16 - (nj - wj0);
        cok[reg] = ((unsigned)dc < 7u) ? 1 : 0;
        bj0[reg] = min(max(dc + (nj - j + 6), 0), 12);
    }

    short8 aq = *(const short8*)&Qb[w * 16 + r16][quad * 8];
    floatx4 S[8];
    #pragma unroll
    for (int jt = 0; jt < 8; jt++) {
        floatx4 z = {0.f, 0.f, 0.f, 0.f};
        short8 bk = *(const short8*)&Kt[(kt0 + jt) * 16 + r16][quad * 8];
        S[jt] = __builtin_amdgcn_mfma_f32_16x16x32_bf16(aq, bk, z, 0, 0, 0);
    }
    const float scale = 0.17677669529663688110f;
    #pragma unroll
    for (int jt = 0; jt < 8; jt++) {
        #pragma unroll
        for (int reg = 0; reg < 4; reg++) {
            int dr = kt0 + jt - oi[reg];
            bool ok = ((unsigned)dr < 7u) && cok[reg];
            int bi = min(max(dr + ai_[reg], 0), 12);
            float bias = rb[bi * 13 + bj0[reg]];
            S[jt][reg] = ok ? fmaf(S[jt][reg], scale, bias) : -1e30f;
        }
    }
    float rinv[4];
    #pragma unroll
    for (int reg = 0; reg < 4; reg++) {
        float m = S[0][reg];
        #pragma unroll
        for (int jt = 1; jt < 8; jt++) m = fmaxf(m, S[jt][reg]);
        m = fmaxf(m, __shfl_xor(m, 1));
        m = fmaxf(m, __shfl_xor(m, 2));
        m = fmaxf(m, __shfl_xor(m, 4));
        m = fmaxf(m, __shfl_xor(m, 8));
        float s = 0.f;
        #pragma unroll
        for (int jt = 0; jt < 8; jt++) {
            float e = __expf(S[jt][reg] - m);
            S[jt][reg] = e;
            s += e;
        }
        s += __shfl_xor(s, 1);
        s += __shfl_xor(s, 2);
        s += __shfl_xor(s, 4);
        s += __shfl_xor(s, 8);
        rinv[reg] = 1.0f / s;
    }
    #pragma unroll
    for (int jt = 0; jt < 8; jt++)
        #pragma unroll
        for (int reg = 0; reg < 4; reg++)
            Pl[w][quad * 4 + reg][(kt0 + jt) * 16 + r16] = f2bf(S[jt][reg] * rinv[reg]);
    if (kt0 & 1) {   // zero boundary tiles read by the extra PV chunk
        #pragma unroll
        for (int reg = 0; reg < 4; reg++) {
            Pl[w][quad * 4 + reg][(kt0 - 1) * 16 + r16] = 0;
            Pl[w][quad * 4 + reg][(kt0 + 8) * 16 + r16] = 0;
        }
    }

    const int ks0 = kt0 >> 1;
    const int nch = 4 + (kt0 & 1);
    floatx4 O0 = {0.f, 0.f, 0.f, 0.f}, O1 = {0.f, 0.f, 0.f, 0.f};
    #pragma unroll
    for (int c2 = 0; c2 < 5; c2++) {
        if (c2 < nch) {
            int ks = ks0 + c2;
            short8 ap = *(const short8*)&Pl[w][r16][ks * 32 + quad * 8];
            short8 b0 = *(const short8*)&Vt[r16][ks * 32 + quad * 8];
            short8 b1 = *(const short8*)&Vt[16 + r16][ks * 32 + quad * 8];
            O0 = __builtin_amdgcn_mfma_f32_16x16x32_bf16(ap, b0, O0, 0, 0, 0);
            O1 = __builtin_amdgcn_mfma_f32_16x16x32_bf16(ap, b1, O1, 0, 0, 0);
        }
    }
    #pragma unroll
    for (int reg = 0; reg < 4; reg++) {
        int q = w * 16 + quad * 4 + reg;
        size_t m = (size_t)((n * HH + i0 + (q >> 3)) * WW + j0 + (q & 7));
        outp[m * CC + h * DD + r16]      = f2bf(O0[reg]);
        outp[m * CC + h * DD + 16 + r16] = f2bf(O1[reg]);
    }
}

// ---------------- fused tail: 16 rows/block, wave = column split ------
// grid 1024, ~31 KB LDS -> 4+ blocks/CU resident. Wave w: proj/fc2 cols
// [w*32, w*32+32), fc1 cols [w*128, w*128+128). x2 in registers (proj and
// fc2 col-maps coincide). st overlays xs (xs dead before fc2 epilogue).
__global__ __launch_bounds__(256) void tail_kernel(
    const BF* __restrict__ A, const BF* __restrict__ projT2,
    const float* __restrict__ proj_b, const float* __restrict__ x,
    const BF* __restrict__ tbuf, const float* __restrict__ part,
    const float* __restrict__ ca1_w, const float* __restrict__ ca1_b,
    const float* __restrict__ ca2_w, const float* __restrict__ ca2_b,
    const float* __restrict__ w2, const float* __restrict__ b2,
    const BF* __restrict__ fc1T2, const float* __restrict__ fc1_b,
    const BF* __restrict__ fc2T2, const float* __restrict__ fc2_b,
    float* __restrict__ out)
{
    __shared__ __align__(16) char sarena[9216];     // xs [16][132] f32 / st [128][18] f32
    __shared__ __align__(16) BF ln2l[16][136];      // 4352 B
    __shared__ __align__(16) BF hl[16][520];        // 16640 B
    __shared__ float gs[128], h1s[8], gl[128];
    __shared__ float S1[4][16], S2[4][16];

    float* xs = (float*)sarena;    // [p][c] stride 132
    float* st = (float*)sarena;    // [c][p] stride 18

    const int t = threadIdx.x;
    const int w = t >> 6, lane = t & 63, quad = lane >> 4, r16 = lane & 15;
    const int row0 = blockIdx.x * 16;
    const int n = row0 >> 12, p0 = row0 & 4095;

    // ---- stage x tile: 128 c x 16 p, coalesced float4 along p ----
    #pragma unroll
    for (int it = 0; it < 2; it++) {
        int idx4 = it * 256 + t;
        int p4 = idx4 & 3, c = idx4 >> 2;
        float4 v = *(const float4*)(x + (size_t)(n * CC + c) * HW + p0 + p4 * 4);
        xs[(p4 * 4 + 0) * 132 + c] = v.x; xs[(p4 * 4 + 1) * 132 + c] = v.y;
        xs[(p4 * 4 + 2) * 132 + c] = v.z; xs[(p4 * 4 + 3) * 132 + c] = v.w;
    }
    if (t < 128) gs[t] = part[n * CC + t] * (1.0f / HW);
    __syncthreads();
    if (t < 7) {
        float a = ca1_b[t];
        for (int k = 0; k < 128; k++) a += gs[k] * ca1_w[k * 7 + t];
        h1s[t] = fmaxf(a, 0.f);
    }
    __syncthreads();
    if (t < 128) {
        float o = ca2_b[t];
        #pragma unroll
        for (int r = 0; r < 7; r++) o += h1s[r] * ca2_w[r * 128 + t];
        gl[t] = 1.0f / (1.0f + expf(-o));
    }

    // ---- proj: wave = 16 rows x 32 cols ----
    floatx4 acc[2] = {};
    const BF* arow = A + (size_t)(row0 + r16) * CC;
    #pragma unroll
    for (int ks = 0; ks < 4; ks++) {
        short8 af = *(const short8*)(arow + ks * 32 + quad * 8);
        #pragma unroll
        for (int nt = 0; nt < 2; nt++) {
            int col = w * 32 + nt * 16 + r16;
            short8 bf = *(const short8*)(projT2 + ((size_t)(ks * 128 + col)) * 32 + quad * 8);
            acc[nt] = __builtin_amdgcn_mfma_f32_16x16x32_bf16(af, bf, acc[nt], 0, 0, 0);
        }
    }
    __syncthreads();   // gl ready

    // ---- x2 (registers) + LN2 stats ----
    float x2r[2][4];
    float s1[4] = {0.f, 0.f, 0.f, 0.f}, s2[4] = {0.f, 0.f, 0.f, 0.f};
    #pragma unroll
    for (int nt = 0; nt < 2; nt++) {
        int col = w * 32 + nt * 16 + r16;
        float bv = proj_b[col], gv = gl[col];
        #pragma unroll
        for (int reg = 0; reg < 4; reg++) {
            int lr = quad * 4 + reg;
            float tv = bf2f(tbuf[(size_t)(row0 + lr) * CC + col]);
            float v = acc[nt][reg] + bv + xs[lr * 132 + col] + 0.02f * tv * gv;
            x2r[nt][reg] = v;
            s1[reg] += v; s2[reg] += v * v;
        }
    }
    #pragma unroll
    for (int reg = 0; reg < 4; reg++) {
        #pragma unroll
        for (int off = 1; off < 16; off <<= 1) {
            s1[reg] += __shfl_xor(s1[reg], off);
            s2[reg] += __shfl_xor(s2[reg], off);
        }
    }
    if (r16 == 0) {
        #pragma unroll
        for (int reg = 0; reg < 4; reg++) {
            S1[w][quad * 4 + reg] = s1[reg];
            S2[w][quad * 4 + reg] = s2[reg];
        }
    }
    __syncthreads();
    float mu[4], rr[4];
    #pragma unroll
    for (int reg = 0; reg < 4; reg++) {
        int r = quad * 4 + reg;
        float t1 = S1[0][r] + S1[1][r] + S1[2][r] + S1[3][r];
        float t2 = S2[0][r] + S2[1][r] + S2[2][r] + S2[3][r];
        mu[reg] = t1 * (1.0f / CC);
        float var = t2 * (1.0f / CC) - mu[reg] * mu[reg];
        rr[reg] = rsqrtf(var + 1e-5f);
    }
    #pragma unroll
    for (int nt = 0; nt < 2; nt++) {
        int col = w * 32 + nt * 16 + r16;
        float wv = w2[col], bv2 = b2[col];
        #pragma unroll
        for (int reg = 0; reg < 4; reg++) {
            int lr = quad * 4 + reg;
            ln2l[lr][col] = f2bf((x2r[nt][reg] - mu[reg]) * rr[reg] * wv + bv2);
        }
    }
    __syncthreads();   // ln2l ready

    // ---- fc1: wave = 16 rows x 128 cols, gelu -> hl ----
    short8 af1[4];
    #pragma unroll
    for (int ks = 0; ks < 4; ks++)
        af1[ks] = *(const short8*)&ln2l[r16][ks * 32 + quad * 8];
    floatx4 a2[8] = {};
    #pragma unroll
    for (int ks = 0; ks < 4; ks++) {
        #pragma unroll
        for (int nt = 0; nt < 8; nt++) {
            int col = w * 128 + nt * 16 + r16;
            short8 bf = *(const short8*)(fc1T2 + ((size_t)(ks * 512 + col)) * 32 + quad * 8);
            a2[nt] = __builtin_amdgcn_mfma_f32_16x16x32_bf16(af1[ks], bf, a2[nt], 0, 0, 0);
        }
    }
    #pragma unroll
    for (int nt = 0; nt < 8; nt++) {
        int col = w * 128 + nt * 16 + r16;
        float bv = fc1_b[col];
        #pragma unroll
        for (int reg = 0; reg < 4; reg++) {
            int lr = quad * 4 + reg;
            hl[lr][col] = f2bf(gelu_f(a2[nt][reg] + bv));
        }
    }
    __syncthreads();   // hl ready

    // ---- fc2: wave = 16 rows x 32 cols, K=512 ----
    floatx4 a3[2] = {};
    #pragma unroll
    for (int ks = 0; ks < 16; ks++) {
        short8 af = *(const short8*)&hl[r16][ks * 32 + quad * 8];
        #pragma unroll
        for (int nt = 0; nt < 2; nt++) {
            int col = w * 32 + nt * 16 + r16;
            short8 bf = *(const short8*)(fc2T2 + ((size_t)(ks * 128 + col)) * 32 + quad * 8);
            a3[nt] = __builtin_amdgcn_mfma_f32_16x16x32_bf16(af, bf, a3[nt], 0, 0, 0);
        }
    }
    __syncthreads();   // xs long dead; st overlay safe
    #pragma unroll
    for (int nt = 0; nt < 2; nt++) {
        int col = w * 32 + nt * 16 + r16;
        float bv = fc2_b[col];
        #pragma unroll
        for (int reg = 0; reg < 4; reg++) {
            int lr = quad * 4 + reg;
            st[col * 18 + lr] = a3[nt][reg] + bv + x2r[nt][reg];
        }
    }
    __syncthreads();
    {   // coalesced NCHW store: 128 cols x 16 p
        int col = t >> 1, half = t & 1;
        float* dst = out + (size_t)(n * CC + col) * HW + p0 + half * 8;
        #pragma unroll
        for (int u = 0; u < 2; u++) {
            float4 v;
            v.x = st[col * 18 + half * 8 + u * 4 + 0];
            v.y = st[col * 18 + half * 8 + u * 4 + 1];
            v.z = st[col * 18 + half * 8 + u * 4 + 2];
            v.w = st[col * 18 + half * 8 + u * 4 + 3];
            *(float4*)(dst + u * 4) = v;
        }
    }
}

extern "C" void kernel_launch(void* const* d_in, const int* in_sizes, int n_in,
                              void* d_out, int out_size, void* d_ws, size_t ws_size,
                              hipStream_t stream)
{
    const float* x       = (const float*)d_in[0];
    const float* ln1_w   = (const float*)d_in[1];
    const float* ln1_b   = (const float*)d_in[2];
    const float* ln2_w   = (const float*)d_in[3];
    const float* ln2_b   = (const float*)d_in[4];
    const float* qkv_w   = (const float*)d_in[5];
    const float* qkv_b   = (const float*)d_in[6];
    const float* proj_w  = (const float*)d_in[7];
    const float* proj_b  = (const float*)d_in[8];
    const float* rpb     = (const float*)d_in[9];
    const float* conv1_w = (const float*)d_in[10];
    const float* conv1_b = (const float*)d_in[11];
    const float* conv2_w = (const float*)d_in[12];
    const float* conv2_b = (const float*)d_in[13];
    const float* ca1_w   = (const float*)d_in[14];
    const float* ca1_b   = (const float*)d_in[15];
    const float* ca2_w   = (const float*)d_in[16];
    const float* ca2_b   = (const float*)d_in[17];
    const float* fc1_w   = (const float*)d_in[18];
    const float* fc1_b   = (const float*)d_in[19];
    const float* fc2_w   = (const float*)d_in[20];
    const float* fc2_b   = (const float*)d_in[21];
    float* out = (float*)d_out;

    char* ws = (char*)d_ws;
    BF*    xn_bf   = (BF*)(ws);                  // M*128*2 = 4 MB
    BF*    qkv_bf  = (BF*)(ws + 4194304);        // M*384*2 = 12 MB
    BF*    t_bf    = (BF*)(ws + 16777216);       // M*128*2 = 4 MB
    BF*    na_bf   = (BF*)(ws + 20971520);       // M*128*2 = 4 MB
    float* part    = (float*)(ws + 25165824);    // 2 KB
    BF*    qkvT    = (BF*)(ws + 25167872);       // 98304 B
    BF*    c1T     = (BF*)(ws + 25266176);       // 8192 B
    BF*    c2T     = (BF*)(ws + 25274368);       // 8192 B
    BF*    projT2  = (BF*)(ws + 25282560);       // 32768 B
    BF*    fc1T2   = (BF*)(ws + 25315328);       // 131072 B
    BF*    fc2T2   = (BF*)(ws + 25446400);       // 131072 B

    // 1. LN1 transpose-tile + one-time weight prep (blocks 512..639)
    ln1t_kernel<<<640, 256, 0, stream>>>(x, ln1_w, ln1_b, xn_bf, part,
        qkv_w, conv1_w, conv2_w, proj_w, fc1_w, fc2_w,
        qkvT, c1T, c2T, projT2, fc1T2, fc2T2);
    // 2. qkv GEMM (2 row-tiles/block) + conv-MLP, one launch
    phase2<<<1024, 256, 0, stream>>>(xn_bf, qkvT, qkv_b, qkv_bf,
                                     c1T, conv1_b, c2T, conv2_b, t_bf, part);
    // 3. MFMA neighborhood attention (tile-pruned)
    na_mfma_kernel<<<1024, 256, 0, stream>>>(qkv_bf, rpb, na_bf);
    // 4. fused tail: 16 rows/block, grid 1024
    tail_kernel<<<1024, 256, 0, stream>>>(na_bf, projT2, proj_b, x, t_bf, part,
                                          ca1_w, ca1_b, ca2_w, ca2_b,
                                          ln2_w, ln2_b, fc1T2, fc1_b,
                                          fc2T2, fc2_b, out);
}